// Round 5
// baseline (103.671 us; speedup 1.0000x reference)
//
#include <hip/hip_runtime.h>

// Problem constants (from reference)
#define NN     1024      // nodes
#define INDIM  64
#define EREAL  16384
#define HD     64        // H*D = 8*8

// GAMMA = 0.1 ; C = GAMMA/(1+GAMMA) ; scale = sqrt(D)=sqrt(8)
constexpr float C_BASE    = 0.1f / 1.1f;
constexpr float INV_1P1   = 1.0f / 1.1f;
constexpr float INV_SCALE = 0.35355339059327373f;  // 1/sqrt(8)

// broadcast lane `lane`'s value to all lanes as a wave-uniform (SGPR) float
__device__ __forceinline__ float bcast(float v, int lane) {
    return __uint_as_float(__builtin_amdgcn_readlane(__float_as_uint(v), lane));
}

// ---- Kernel A: proj | zero winner | zero accumulators | h column-sum partials
// blocks   0..255 : node projections (4 rows each)
// blocks 256..511 : zero winner (4 MiB)
// blocks 512..583 : zero outacc+zacc (288 KiB, contiguous)
// blocks 584..599 : partial column sums of h (for S = hsum @ WV)
__global__ __launch_bounds__(256)
void prep_kernel(const float* __restrict__ h,
                 const float* __restrict__ WQ,
                 const float* __restrict__ WK,
                 const float* __restrict__ WV,
                 float* __restrict__ Qh,
                 float* __restrict__ Kh,
                 float* __restrict__ Vh,
                 float* __restrict__ Spart,   // [16][INDIM] partial column sums of h
                 float* __restrict__ outacc,  // contiguous with zacc
                 int*   __restrict__ winner)
{
    const int tid = threadIdx.x;
    const int bid = blockIdx.x;
    const int g = tid >> 6, c = tid & 63;
    __shared__ float lds_buf[4][64];
    const float4 zero4 = make_float4(0.f, 0.f, 0.f, 0.f);

    if (bid < 256) {
        // node projections: rows bid*4 .. bid*4+3
        const int row = bid * 4 + g;
        lds_buf[g][c] = h[row * INDIM + c];
        __syncthreads();
        float q = 0.f, k = 0.f, v = 0.f;
#pragma unroll
        for (int r = 0; r < INDIM; ++r) {
            const float hv = lds_buf[g][r];
            q = fmaf(hv, WQ[r * HD + c], q);
            k = fmaf(hv, WK[r * HD + c], k);
            v = fmaf(hv, WV[r * HD + c], v);
        }
        Qh[row * HD + c] = q;
        Kh[row * HD + c] = k;
        Vh[row * HD + c] = v;
    } else if (bid < 512) {
        // zero winner: 262144 float4 = 4 MiB
        const int idx = (bid - 256) * 256 + tid;
        float4* w4 = (float4*)winner;
#pragma unroll
        for (int i = 0; i < 4; ++i) w4[idx + i * 65536] = zero4;
    } else if (bid < 584) {
        // zero outacc(65536f)+zacc(8192f) = 18432 float4 = 288 KiB
        const int idx = (bid - 512) * 256 + tid;
        ((float4*)outacc)[idx] = zero4;
    } else {
        // partial column sums of h: chunk p = 64 rows
        const int p = bid - 584;                        // 0..15
        float s = 0.f;
        const int j0 = p * 64 + g * 16;
        for (int j = j0; j < j0 + 16; ++j) s += h[j * INDIM + c];
        lds_buf[g][c] = s;
        __syncthreads();
        if (g == 0)
            Spart[p * INDIM + c] = lds_buf[0][c] + lds_buf[1][c] + lds_buf[2][c] + lds_buf[3][c];
    }
}

// ---- Kernel B: per-edge delta + inline dedup (dethrone-subtract) + scatter ----
// numpy last-write-wins == max-edge-id-wins. ONE lane per wave does
// ret = atomicMax(winner[key], k+1), then broadcasts ret so all branches are
// wave-uniform (round-4 bug: all 64 lanes did the atomicMax, so lanes 1..63
// observed ret==k+1 and subtracted the edge's own contribution).
//   ret > k+1          -> loser on arrival, contribute nothing
//   ret == 0           -> first claimant, add own delta
//   0 < ret < k+1      -> add own delta AND subtract edge (ret-1)'s delta.
// Every non-final holder is subtracted exactly once (by its unique dethroner);
// adds/subtracts are commutative atomicAdds so no ordering fences are needed.
__global__ __launch_bounds__(256)
void edge_kernel(const float* __restrict__ e,
                 const float* __restrict__ WE,
                 const float* __restrict__ Qh,
                 const float* __restrict__ Kh,
                 const float* __restrict__ Vh,
                 const int*   __restrict__ src,
                 const int*   __restrict__ dst,
                 int*   __restrict__ winner,
                 float* __restrict__ outacc,
                 float* __restrict__ zacc)
{
    const int gtid = blockIdx.x * 256 + threadIdx.x;
    const int wave = gtid >> 6;                      // 0..2047
    const int t    = threadIdx.x & 63;               // lane = h*8+d
    const int k0   = wave * 8;

    float ev[8];
#pragma unroll
    for (int i = 0; i < 8; ++i) ev[i] = e[(k0 + i) * INDIM + t];
    float acc[8] = {0.f, 0.f, 0.f, 0.f, 0.f, 0.f, 0.f, 0.f};
    // Eh[k,t] = sum_r e[k,r]*WE[r,t]; one WE load feeds 8 edges via readlane broadcast
#pragma unroll
    for (int r = 0; r < INDIM; ++r) {
        const float w = WE[r * HD + t];
#pragma unroll
        for (int i = 0; i < 8; ++i)
            acc[i] = fmaf(bcast(ev[i], r), w, acc[i]);
    }
#pragma unroll
    for (int i = 0; i < 8; ++i) {
        const int k = k0 + i;
        const int s = src[k];
        const int d = dst[k];
        if (s == d) continue;                        // diagonal is zeroed in reference
        const float kq = Kh[s * HD + t] * Qh[d * HD + t];
        float term = kq * acc[i];
        term += __shfl_xor(term, 1, 64);
        term += __shfl_xor(term, 2, 64);
        term += __shfl_xor(term, 4, 64);
        const float wr    = fminf(fmaxf(term * INV_SCALE, -5.f), 5.f);
        const float delta = __expf(wr) * INV_1P1 - C_BASE;

        // single-lane atomic, wave-uniform broadcast of the old value
        int ret = 0;
        if (t == 0) ret = atomicMax(&winner[s * NN + d], k + 1);
        ret = __shfl(ret, 0, 64);

        if (ret > k + 1) continue;                   // a later edge already holds the slot
        atomicAdd(&outacc[d * HD + t], delta * Vh[s * HD + t]);
        if ((t & 7) == 0) atomicAdd(&zacc[d * 8 + (t >> 3)], delta);
        if (ret >= 1) {
            // we dethroned edge j = ret-1 (same (s,d)): subtract its contribution
            const int j = ret - 1;
            const float evj = e[j * INDIM + t];
            float accj = 0.f;
#pragma unroll
            for (int r = 0; r < INDIM; ++r)
                accj = fmaf(bcast(evj, r), WE[r * HD + t], accj);
            float termj = kq * accj;
            termj += __shfl_xor(termj, 1, 64);
            termj += __shfl_xor(termj, 2, 64);
            termj += __shfl_xor(termj, 4, 64);
            const float wrj    = fminf(fmaxf(termj * INV_SCALE, -5.f), 5.f);
            const float deltaj = __expf(wrj) * INV_1P1 - C_BASE;
            atomicAdd(&outacc[d * HD + t], -deltaj * Vh[s * HD + t]);
            if ((t & 7) == 0) atomicAdd(&zacc[d * 8 + (t >> 3)], -deltaj);
        }
    }
}

// ---- Kernel C: out[j,t] = (C*(S[t]-Vh[j,t]) + outacc[j,t]) / (C*(N-1) + zacc[j,h] + 1e-6)
// S[t] = (sum_j h[j,:]) @ WV[:,t], assembled per block from Spart.
__global__ __launch_bounds__(256)
void finalize_kernel(const float* __restrict__ WV,
                     const float* __restrict__ Vh,
                     const float* __restrict__ Spart,
                     const float* __restrict__ outacc,
                     const float* __restrict__ zacc,
                     float* __restrict__ out)
{
    const int tid = threadIdx.x;
    __shared__ float sh_hsum[INDIM];
    __shared__ float sh_S[HD];
    if (tid < INDIM) {
        float hs = 0.f;
#pragma unroll
        for (int p = 0; p < 16; ++p) hs += Spart[p * INDIM + tid];
        sh_hsum[tid] = hs;
    }
    __syncthreads();
    if (tid < HD) {
        float s = 0.f;
#pragma unroll
        for (int r = 0; r < INDIM; ++r) s += sh_hsum[r] * WV[r * HD + tid];
        sh_S[tid] = s;
    }
    __syncthreads();
    const int idx = blockIdx.x * 256 + tid;          // 0..65535
    const int j = idx >> 6, t = idx & 63;
    const float z = C_BASE * 1023.f + zacc[j * 8 + (t >> 3)] + 1e-6f;
    out[idx] = fmaf(C_BASE, sh_S[t] - Vh[idx], outacc[idx]) / z;
}

extern "C" void kernel_launch(void* const* d_in, const int* in_sizes, int n_in,
                              void* d_out, int out_size, void* d_ws, size_t ws_size,
                              hipStream_t stream) {
    const float* h  = (const float*)d_in[0];
    const float* e  = (const float*)d_in[1];
    const float* WQ = (const float*)d_in[2];
    const float* WK = (const float*)d_in[3];
    const float* WE = (const float*)d_in[4];
    // d_in[5..7] = WQ2, WK2, WE2 — provably unused: fake weights are overwritten
    // at every real-edge position and equal GAMMA/(1+GAMMA) elsewhere.
    const float* WV = (const float*)d_in[8];
    const int* src  = (const int*)d_in[9];
    const int* dst  = (const int*)d_in[10];
    float* out = (float*)d_out;

    char* ws = (char*)d_ws;
    float* Qh     = (float*)(ws + (0    << 10));   // 256 KB
    float* Kh     = (float*)(ws + (256  << 10));   // 256 KB
    float* Vh     = (float*)(ws + (512  << 10));   // 256 KB
    float* Spart  = (float*)(ws + (768  << 10));   // 4 KB (fully overwritten, no zeroing)
    float* outacc = (float*)(ws + (1024 << 10));   // 256 KB -- zeroed in prep
    float* zacc   = (float*)(ws + (1280 << 10));   // 32 KB  -- contiguous with outacc
    int*   winner = (int*)  (ws + (1312 << 10));   // 4 MB   -- zeroed in prep

    hipLaunchKernelGGL(prep_kernel, dim3(600), dim3(256), 0, stream,
                       h, WQ, WK, WV, Qh, Kh, Vh, Spart, outacc, winner);
    hipLaunchKernelGGL(edge_kernel, dim3(512), dim3(256), 0, stream,
                       e, WE, Qh, Kh, Vh, src, dst, winner, outacc, zacc);
    hipLaunchKernelGGL(finalize_kernel, dim3(256), dim3(256), 0, stream,
                       WV, Vh, Spart, outacc, zacc, out);
}

// Round 6
// 101.884 us; speedup vs baseline: 1.0175x; 1.0175x over previous
//
#include <hip/hip_runtime.h>

// Problem constants (from reference)
#define NN     1024      // nodes
#define INDIM  64
#define EREAL  16384
#define HD     64        // H*D = 8*8

// GAMMA = 0.1 ; C = GAMMA/(1+GAMMA) ; scale = sqrt(D)=sqrt(8)
constexpr float C_BASE    = 0.1f / 1.1f;
constexpr float INV_1P1   = 1.0f / 1.1f;
constexpr float INV_SCALE = 0.35355339059327373f;  // 1/sqrt(8)

// broadcast lane `lane`'s value to all lanes as a wave-uniform (SGPR) float
__device__ __forceinline__ float bcast(float v, int lane) {
    return __uint_as_float(__builtin_amdgcn_readlane(__float_as_uint(v), lane));
}

// ---- Kernel A: proj (blocks 0..255) | winner atomicMax (256..319) | h column-sum partials (320..335)
// All three are independent; winner ordering only needs the preceding memset.
__global__ __launch_bounds__(256)
void prep_kernel(const float* __restrict__ h,
                 const float* __restrict__ WQ,
                 const float* __restrict__ WK,
                 const float* __restrict__ WV,
                 const int*   __restrict__ src,
                 const int*   __restrict__ dst,
                 float* __restrict__ Qh,
                 float* __restrict__ Kh,
                 float* __restrict__ Vh,
                 float* __restrict__ Spart,   // [16][INDIM] partial column sums of h
                 int*   __restrict__ winner)
{
    const int tid = threadIdx.x;
    const int bid = blockIdx.x;
    const int g = tid >> 6, c = tid & 63;
    __shared__ float lds_buf[4][64];

    if (bid < 256) {
        // node projections: rows bid*4 .. bid*4+3
        const int row = bid * 4 + g;
        lds_buf[g][c] = h[row * INDIM + c];
        __syncthreads();
        float q = 0.f, k = 0.f, v = 0.f;
#pragma unroll
        for (int r = 0; r < INDIM; ++r) {
            const float hv = lds_buf[g][r];
            q = fmaf(hv, WQ[r * HD + c], q);
            k = fmaf(hv, WK[r * HD + c], k);
            v = fmaf(hv, WV[r * HD + c], v);
        }
        Qh[row * HD + c] = q;
        Kh[row * HD + c] = k;
        Vh[row * HD + c] = v;
    } else if (bid < 320) {
        // dedup: last edge with a given (src,dst) wins (numpy scatter-set semantics)
        const int k = (bid - 256) * 256 + tid;          // 0..16383
        atomicMax(&winner[src[k] * NN + dst[k]], k + 1);
    } else {
        // partial column sums of h: chunk p = 64 rows
        const int p = bid - 320;                        // 0..15
        float s = 0.f;
        const int j0 = p * 64 + g * 16;
        for (int j = j0; j < j0 + 16; ++j) s += h[j * INDIM + c];
        lds_buf[g][c] = s;
        __syncthreads();
        if (g == 0)
            Spart[p * INDIM + c] = lds_buf[0][c] + lds_buf[1][c] + lds_buf[2][c] + lds_buf[3][c];
    }
}

// ---- Kernel B: per-edge delta + scatter accumulate (8 edges per wave) ----
__global__ __launch_bounds__(256)
void edge_kernel(const float* __restrict__ e,
                 const float* __restrict__ WE,
                 const float* __restrict__ Qh,
                 const float* __restrict__ Kh,
                 const float* __restrict__ Vh,
                 const int*   __restrict__ src,
                 const int*   __restrict__ dst,
                 const int*   __restrict__ winner,
                 float* __restrict__ outacc,
                 float* __restrict__ zacc)
{
    const int gtid = blockIdx.x * 256 + threadIdx.x;
    const int wave = gtid >> 6;                      // 0..2047
    const int t    = threadIdx.x & 63;               // lane = h*8+d
    const int k0   = wave * 8;

    float ev[8];
#pragma unroll
    for (int i = 0; i < 8; ++i) ev[i] = e[(k0 + i) * INDIM + t];
    float acc[8] = {0.f, 0.f, 0.f, 0.f, 0.f, 0.f, 0.f, 0.f};
    // Eh[k,t] = sum_r e[k,r]*WE[r,t]; one WE load feeds 8 edges via readlane broadcast
#pragma unroll
    for (int r = 0; r < INDIM; ++r) {
        const float w = WE[r * HD + t];
#pragma unroll
        for (int i = 0; i < 8; ++i)
            acc[i] = fmaf(bcast(ev[i], r), w, acc[i]);
    }
#pragma unroll
    for (int i = 0; i < 8; ++i) {
        const int k = k0 + i;
        const int s = src[k];
        const int d = dst[k];
        // wave-uniform skip: duplicate losers (last-set-wins) and self-loops
        if (winner[s * NN + d] != k + 1 || s == d) continue;
        float term = Kh[s * HD + t] * Qh[d * HD + t] * acc[i];
        term += __shfl_xor(term, 1, 64);
        term += __shfl_xor(term, 2, 64);
        term += __shfl_xor(term, 4, 64);
        const float wr    = fminf(fmaxf(term * INV_SCALE, -5.f), 5.f);
        const float delta = __expf(wr) * INV_1P1 - C_BASE;
        atomicAdd(&outacc[d * HD + t], delta * Vh[s * HD + t]);
        if ((t & 7) == 0) atomicAdd(&zacc[d * 8 + (t >> 3)], delta);
    }
}

// ---- Kernel C: out[j,t] = (C*(S[t]-Vh[j,t]) + outacc[j,t]) / (C*(N-1) + zacc[j,h] + 1e-6)
// S[t] = (sum_j h[j,:]) @ WV[:,t], assembled per block from Spart.
__global__ __launch_bounds__(256)
void finalize_kernel(const float* __restrict__ WV,
                     const float* __restrict__ Vh,
                     const float* __restrict__ Spart,
                     const float* __restrict__ outacc,
                     const float* __restrict__ zacc,
                     float* __restrict__ out)
{
    const int tid = threadIdx.x;
    __shared__ float sh_hsum[INDIM];
    __shared__ float sh_S[HD];
    if (tid < INDIM) {
        float hs = 0.f;
#pragma unroll
        for (int p = 0; p < 16; ++p) hs += Spart[p * INDIM + tid];
        sh_hsum[tid] = hs;
    }
    __syncthreads();
    if (tid < HD) {
        float s = 0.f;
#pragma unroll
        for (int r = 0; r < INDIM; ++r) s += sh_hsum[r] * WV[r * HD + tid];
        sh_S[tid] = s;
    }
    __syncthreads();
    const int idx = blockIdx.x * 256 + tid;          // 0..65535
    const int j = idx >> 6, t = idx & 63;
    const float z = C_BASE * 1023.f + zacc[j * 8 + (t >> 3)] + 1e-6f;
    out[idx] = fmaf(C_BASE, sh_S[t] - Vh[idx], outacc[idx]) / z;
}

extern "C" void kernel_launch(void* const* d_in, const int* in_sizes, int n_in,
                              void* d_out, int out_size, void* d_ws, size_t ws_size,
                              hipStream_t stream) {
    const float* h  = (const float*)d_in[0];
    const float* e  = (const float*)d_in[1];
    const float* WQ = (const float*)d_in[2];
    const float* WK = (const float*)d_in[3];
    const float* WE = (const float*)d_in[4];
    // d_in[5..7] = WQ2, WK2, WE2 — provably unused: fake weights are overwritten
    // at every real-edge position and equal GAMMA/(1+GAMMA) elsewhere.
    const float* WV = (const float*)d_in[8];
    const int* src  = (const int*)d_in[9];
    const int* dst  = (const int*)d_in[10];
    float* out = (float*)d_out;

    char* ws = (char*)d_ws;
    float* Qh     = (float*)(ws + (0    << 10));   // 256 KB
    float* Kh     = (float*)(ws + (256  << 10));   // 256 KB
    float* Vh     = (float*)(ws + (512  << 10));   // 256 KB
    float* Spart  = (float*)(ws + (768  << 10));   // 4 KB (fully overwritten, no zeroing)
    // zeroed region: outacc(256K) + zacc(32K) + winner(4M), contiguous
    float* outacc = (float*)(ws + (1024 << 10));
    float* zacc   = (float*)(ws + (1280 << 10));
    int*   winner = (int*)  (ws + (1312 << 10));
    const size_t zbytes = (288 << 10) + (4u << 20);

    hipMemsetAsync(outacc, 0, zbytes, stream);
    hipLaunchKernelGGL(prep_kernel, dim3(336), dim3(256), 0, stream,
                       h, WQ, WK, WV, src, dst, Qh, Kh, Vh, Spart, winner);
    hipLaunchKernelGGL(edge_kernel, dim3(512), dim3(256), 0, stream,
                       e, WE, Qh, Kh, Vh, src, dst, winner, outacc, zacc);
    hipLaunchKernelGGL(finalize_kernel, dim3(256), dim3(256), 0, stream,
                       WV, Vh, Spart, outacc, zacc, out);
}